// Round 1
// baseline (3128.272 us; speedup 1.0000x reference)
//
#include <hip/hip_runtime.h>
#include <math.h>

#define N_NODES  50000
#define N_EDGES  800000
#define N_GRAPHS 500
#define NH       16
#define MHID     256
#define RN       128
#define TLOG     11
#define TSIZE    (1 << TLOG)   /* 2048 intervals, TSIZE+1 table rows */
#define RO_NODES 32

__device__ __forceinline__ float selu_f(float v) {
    const float scale = 1.0507009873554805f;
    const float alpha = 1.6732632423543772f;
    return v > 0.f ? scale * v : scale * alpha * (expf(v) - 1.f);
}

__device__ __forceinline__ float sigmoid_f(float v) {
    return 1.f / (1.f + expf(-v));
}

// ---------------------------------------------------------------------------
// Build a(e), be(e) lookup tables on a uniform grid over e in [0,1].
// a(e) is exactly the reference MLP evaluated at grid points; per-edge values
// are obtained by linear interpolation (curvature of a(e) ~0.02 -> lerp error
// ~1e-8, far below the 4.2e-2 threshold).
// ---------------------------------------------------------------------------
__global__ void build_tables(const float* __restrict__ W_l1, const float* __restrict__ b_l1,
                             const float* __restrict__ W_l2, const float* __restrict__ b_l2,
                             const float* __restrict__ W_b1, const float* __restrict__ b_b1,
                             const float* __restrict__ W_b2, const float* __restrict__ b_b2,
                             float* __restrict__ a_table, float* __restrict__ be_table) {
    __shared__ float hid[MHID];
    __shared__ float hidb[MHID];
    int t = blockIdx.x;          // 0..TSIZE
    int j = threadIdx.x;         // 0..255
    float ev = (float)t / (float)TSIZE;
    hid[j]  = selu_f(ev * W_l1[j] + b_l1[j]);
    hidb[j] = selu_f(ev * W_b1[j] + b_b1[j]);
    __syncthreads();
    float acc = b_l2[j];
    for (int k = 0; k < MHID; ++k)
        acc += hid[k] * W_l2[k * 256 + j];
    a_table[(size_t)t * 256 + j] = acc;
    if (j < NH) {
        float accb = b_b2[j];
        for (int k = 0; k < MHID; ++k)
            accb += hidb[k] * W_b2[k * NH + j];
        be_table[t * NH + j] = accb;
    }
}

__global__ void init_h(const float* __restrict__ x, float* __restrict__ h) {
    int n = blockIdx.x * blockDim.x + threadIdx.x;
    if (n >= N_NODES) return;
    float4* hp = (float4*)(h + (size_t)n * 16);
    hp[0] = make_float4(x[n * 2 + 0], x[n * 2 + 1], 0.f, 0.f);
    hp[1] = make_float4(0.f, 0.f, 0.f, 0.f);
    hp[2] = make_float4(0.f, 0.f, 0.f, 0.f);
    hp[3] = make_float4(0.f, 0.f, 0.f, 0.f);
}

// ---------------------------------------------------------------------------
// One message-passing edge pass: m[second] += lerp_a(e) @ h[first] + lerp_be(e)
// 16 lanes per edge (lane = output row i); the group's two 1KB table rows are
// read fully coalesced.
// ---------------------------------------------------------------------------
__global__ void edge_pass(const float* __restrict__ e, const int* __restrict__ first,
                          const int* __restrict__ second,
                          const float* __restrict__ a_table, const float* __restrict__ be_table,
                          const float* __restrict__ h, float* __restrict__ m) {
    __shared__ float hg[16][16];
    int lane = threadIdx.x & 15;
    int grp  = threadIdx.x >> 4;             // 0..15, fully inside one wave
    int eidx = blockIdx.x * 16 + grp;
    if (eidx >= N_EDGES) return;

    float ev = e[eidx];
    float s  = ev * (float)TSIZE;
    int   t  = (int)s;
    t = max(0, min(t, TSIZE - 1));
    float f  = s - (float)t;

    int src = first[eidx];
    hg[grp][lane] = h[(size_t)src * 16 + lane];   // same-wave LDS write/read: lockstep-safe

    const float4* A0 = (const float4*)(a_table + (size_t)t * 256 + lane * 16);
    const float4* A1 = (const float4*)(a_table + (size_t)(t + 1) * 256 + lane * 16);
    float b0 = be_table[t * NH + lane];
    float b1 = be_table[(t + 1) * NH + lane];
    float acc = b0 + f * (b1 - b0);

    const float4* hq4 = (const float4*)hg[grp];
    #pragma unroll
    for (int q = 0; q < 4; ++q) {
        float4 a0 = A0[q];
        float4 a1 = A1[q];
        float4 hq = hq4[q];
        acc += (a0.x + f * (a1.x - a0.x)) * hq.x;
        acc += (a0.y + f * (a1.y - a0.y)) * hq.y;
        acc += (a0.z + f * (a1.z - a0.z)) * hq.z;
        acc += (a0.w + f * (a1.w - a0.w)) * hq.w;
    }
    atomicAdd(&m[(size_t)second[eidx] * 16 + lane], acc);
}

// ---------------------------------------------------------------------------
// GRU cell (reset_after=True), one thread per node.
// ---------------------------------------------------------------------------
__global__ void gru_update(float* __restrict__ h, const float* __restrict__ m,
                           const float* __restrict__ Wx, const float* __restrict__ Uh,
                           const float* __restrict__ bx, const float* __restrict__ bh) {
    __shared__ float sWx[16 * 48];
    __shared__ float sUh[16 * 48];
    __shared__ float sb[96];
    for (int i = threadIdx.x; i < 768; i += blockDim.x) { sWx[i] = Wx[i]; sUh[i] = Uh[i]; }
    if (threadIdx.x < 48) { sb[threadIdx.x] = bx[threadIdx.x]; sb[48 + threadIdx.x] = bh[threadIdx.x]; }
    __syncthreads();

    int n = blockIdx.x * blockDim.x + threadIdx.x;
    if (n >= N_NODES) return;

    float hv[16], mv[16];
    const float4* hp = (const float4*)(h + (size_t)n * 16);
    const float4* mp = (const float4*)(m + (size_t)n * 16);
    #pragma unroll
    for (int q = 0; q < 4; ++q) {
        float4 a = hp[q]; float4 b = mp[q];
        hv[q * 4 + 0] = a.x; hv[q * 4 + 1] = a.y; hv[q * 4 + 2] = a.z; hv[q * 4 + 3] = a.w;
        mv[q * 4 + 0] = b.x; mv[q * 4 + 1] = b.y; mv[q * 4 + 2] = b.z; mv[q * 4 + 3] = b.w;
    }

    float hnew[16];
    #pragma unroll
    for (int i = 0; i < 16; ++i) {
        float xz = sb[i], xr = sb[16 + i], xh = sb[32 + i];
        float hz = sb[48 + i], hr = sb[64 + i], hhp = sb[80 + i];
        #pragma unroll
        for (int k = 0; k < 16; ++k) {
            xz  += mv[k] * sWx[k * 48 + i];
            xr  += mv[k] * sWx[k * 48 + 16 + i];
            xh  += mv[k] * sWx[k * 48 + 32 + i];
            hz  += hv[k] * sUh[k * 48 + i];
            hr  += hv[k] * sUh[k * 48 + 16 + i];
            hhp += hv[k] * sUh[k * 48 + 32 + i];
        }
        float z  = sigmoid_f(xz + hz);
        float r  = sigmoid_f(xr + hr);
        float hc = tanhf(xh + r * hhp);
        hnew[i] = z * hv[i] + (1.f - z) * hc;
    }

    float4* ho = (float4*)(h + (size_t)n * 16);
    #pragma unroll
    for (int q = 0; q < 4; ++q)
        ho[q] = make_float4(hnew[q * 4 + 0], hnew[q * 4 + 1], hnew[q * 4 + 2], hnew[q * 4 + 3]);
}

// ---------------------------------------------------------------------------
// Readout: per node compute RR*j (128-dim), accumulate into nb[segment].
// segment is sorted -> register-accumulate per thread, atomic only on change.
// ---------------------------------------------------------------------------
__global__ void readout(const float* __restrict__ h, const float* __restrict__ x,
                        const int* __restrict__ segment,
                        const float* __restrict__ W_i, const float* __restrict__ b_i,
                        const float* __restrict__ W_R, const float* __restrict__ b_R,
                        const float* __restrict__ W_j1, const float* __restrict__ b_j1,
                        const float* __restrict__ W_j2, const float* __restrict__ b_j2,
                        float* __restrict__ nb) {
    __shared__ float hx[RO_NODES][18];
    __shared__ float il[RO_NODES][RN];
    __shared__ float jl[RO_NODES][RN];
    int node0 = blockIdx.x * RO_NODES;
    int nn = min(RO_NODES, N_NODES - node0);
    int tid = threadIdx.x;                    // 0..127

    for (int idx = tid; idx < nn * 18; idx += 128) {
        int n = idx / 18, k = idx % 18;
        hx[n][k] = (k < 16) ? h[(size_t)(node0 + n) * 16 + k]
                            : x[(size_t)(node0 + n) * 2 + (k - 16)];
    }
    __syncthreads();

    int j = tid;
    for (int n = 0; n < nn; ++n) {
        float ai = b_i[j], aj = b_j1[j];
        #pragma unroll
        for (int k = 0; k < 18; ++k) {
            float hv = hx[n][k];
            ai += hv * W_i[k * RN + j];
            aj += hv * W_j1[k * RN + j];
        }
        il[n][j] = tanhf(ai);
        jl[n][j] = selu_f(aj);
    }
    __syncthreads();

    float acc = 0.f;
    int cur = segment[node0];
    for (int n = 0; n < nn; ++n) {
        int seg = segment[node0 + n];
        if (seg != cur) { atomicAdd(&nb[(size_t)cur * RN + j], acc); acc = 0.f; cur = seg; }
        float ar = b_R[j], a2 = b_j2[j];
        for (int k = 0; k < RN; ++k) {
            ar += il[n][k] * W_R[k * RN + j];
            a2 += jl[n][k] * W_j2[k * RN + j];
        }
        acc += sigmoid_f(ar) * a2;
    }
    atomicAdd(&nb[(size_t)cur * RN + j], acc);
}

// ---------------------------------------------------------------------------
// Final head: out[g] = selu(nb[g] @ W_f1 + b_f1) @ W_f2 + b_f2
// ---------------------------------------------------------------------------
__global__ void final_head(const float* __restrict__ nb, const float* __restrict__ W_f1,
                           const float* __restrict__ b_f1, const float* __restrict__ W_f2,
                           const float* __restrict__ b_f2, float* __restrict__ out) {
    __shared__ float row[128];
    __shared__ float red[128];
    int g = blockIdx.x, j = threadIdx.x;
    row[j] = nb[(size_t)g * 128 + j];
    __syncthreads();
    float a = b_f1[j];
    for (int k = 0; k < 128; ++k)
        a += row[k] * W_f1[k * 128 + j];
    red[j] = selu_f(a) * W_f2[j];
    __syncthreads();
    for (int s2 = 64; s2 > 0; s2 >>= 1) {
        if (j < s2) red[j] += red[j + s2];
        __syncthreads();
    }
    if (j == 0) out[g] = red[0] + b_f2[0];
}

extern "C" void kernel_launch(void* const* d_in, const int* in_sizes, int n_in,
                              void* d_out, int out_size, void* d_ws, size_t ws_size,
                              hipStream_t stream) {
    const float* x    = (const float*)d_in[0];
    const float* e    = (const float*)d_in[1];
    const float* W_l1 = (const float*)d_in[2];
    const float* b_l1 = (const float*)d_in[3];
    const float* W_l2 = (const float*)d_in[4];
    const float* b_l2 = (const float*)d_in[5];
    const float* W_b1 = (const float*)d_in[6];
    const float* b_b1 = (const float*)d_in[7];
    const float* W_b2 = (const float*)d_in[8];
    const float* b_b2 = (const float*)d_in[9];
    const float* gWx  = (const float*)d_in[10];
    const float* gUh  = (const float*)d_in[11];
    const float* gbx  = (const float*)d_in[12];
    const float* gbh  = (const float*)d_in[13];
    const float* W_i  = (const float*)d_in[14];
    const float* b_i  = (const float*)d_in[15];
    const float* W_R  = (const float*)d_in[16];
    const float* b_R  = (const float*)d_in[17];
    const float* W_j1 = (const float*)d_in[18];
    const float* b_j1 = (const float*)d_in[19];
    const float* W_j2 = (const float*)d_in[20];
    const float* b_j2 = (const float*)d_in[21];
    const float* W_f1 = (const float*)d_in[22];
    const float* b_f1 = (const float*)d_in[23];
    const float* W_f2 = (const float*)d_in[24];
    const float* b_f2 = (const float*)d_in[25];
    const int* first   = (const int*)d_in[26];
    const int* second  = (const int*)d_in[27];
    const int* segment = (const int*)d_in[28];
    float* out = (float*)d_out;

    float* ws       = (float*)d_ws;
    float* a_table  = ws;                                       // (TSIZE+1)*256
    float* be_table = a_table + (size_t)(TSIZE + 1) * 256;      // (TSIZE+1)*16
    float* h        = be_table + (size_t)(TSIZE + 1) * 16;      // N*16
    float* m        = h + (size_t)N_NODES * 16;                 // N*16
    float* nb       = m + (size_t)N_NODES * 16;                 // G*128

    build_tables<<<TSIZE + 1, 256, 0, stream>>>(W_l1, b_l1, W_l2, b_l2,
                                                W_b1, b_b1, W_b2, b_b2,
                                                a_table, be_table);
    init_h<<<(N_NODES + 255) / 256, 256, 0, stream>>>(x, h);

    for (int p = 0; p < 8; ++p) {
        hipMemsetAsync(m, 0, (size_t)N_NODES * 16 * sizeof(float), stream);
        edge_pass<<<N_EDGES / 16, 256, 0, stream>>>(e, first, second, a_table, be_table, h, m);
        gru_update<<<(N_NODES + 255) / 256, 256, 0, stream>>>(h, m, gWx, gUh, gbx, gbh);
    }

    hipMemsetAsync(nb, 0, (size_t)N_GRAPHS * 128 * sizeof(float), stream);
    readout<<<(N_NODES + RO_NODES - 1) / RO_NODES, 128, 0, stream>>>(
        h, x, segment, W_i, b_i, W_R, b_R, W_j1, b_j1, W_j2, b_j2, nb);
    final_head<<<N_GRAPHS, 128, 0, stream>>>(nb, W_f1, b_f1, W_f2, b_f2, out);
}

// Round 2
// 1071.115 us; speedup vs baseline: 2.9206x; 2.9206x over previous
//
#include <hip/hip_runtime.h>
#include <math.h>

#define N_NODES  50000
#define N_EDGES  800000
#define N_GRAPHS 500
#define NH       16
#define MHID     256
#define RN       128
#define TSIZE    2048
#define RO       32

__device__ __forceinline__ float selu_f(float v) {
    const float scale = 1.0507009873554805f;
    const float alpha = 1.6732632423543772f;
    return v > 0.f ? scale * v : scale * alpha * (expf(v) - 1.f);
}
__device__ __forceinline__ float sigmoid_f(float v) { return 1.f / (1.f + expf(-v)); }
__device__ __forceinline__ float bf_lo(unsigned u) { return __uint_as_float(u << 16); }
__device__ __forceinline__ float bf_hi(unsigned u) { return __uint_as_float(u & 0xffff0000u); }

// ---------------------------------------------------------------------------
// Tables: T[t] = a(t/TSIZE) fp32 rows (2049 x 256); be rows (2049 x 16).
// ---------------------------------------------------------------------------
__global__ void build_tables(const float* __restrict__ W_l1, const float* __restrict__ b_l1,
                             const float* __restrict__ W_l2, const float* __restrict__ b_l2,
                             const float* __restrict__ W_b1, const float* __restrict__ b_b1,
                             const float* __restrict__ W_b2, const float* __restrict__ b_b2,
                             float* __restrict__ a_table, float* __restrict__ be_table) {
    __shared__ float hid[MHID];
    __shared__ float hidb[MHID];
    int t = blockIdx.x;          // 0..TSIZE
    int j = threadIdx.x;         // 0..255
    float ev = (float)t / (float)TSIZE;
    hid[j]  = selu_f(ev * W_l1[j] + b_l1[j]);
    hidb[j] = selu_f(ev * W_b1[j] + b_b1[j]);
    __syncthreads();
    float acc = b_l2[j];
    for (int k = 0; k < MHID; ++k)
        acc += hid[k] * W_l2[k * 256 + j];
    a_table[(size_t)t * 256 + j] = acc;
    if (j < NH) {
        float accb = b_b2[j];
        for (int k = 0; k < MHID; ++k)
            accb += hidb[k] * W_b2[k * NH + j];
        be_table[t * NH + j] = accb;
    }
}

// D[t] = bf16(T[t+1]-T[t]), 2048 x 256
__global__ void build_diff(const float* __restrict__ T, unsigned short* __restrict__ D) {
    int t = blockIdx.x, j = threadIdx.x;
    float d = T[(size_t)(t + 1) * 256 + j] - T[(size_t)t * 256 + j];
    unsigned u = __float_as_uint(d);
    // round-to-nearest-even bf16
    unsigned r = (u + 0x7fffu + ((u >> 16) & 1u)) >> 16;
    D[(size_t)t * 256 + j] = (unsigned short)r;
}

__global__ void init_h(const float* __restrict__ x, float* __restrict__ h) {
    int n = blockIdx.x * blockDim.x + threadIdx.x;
    if (n >= N_NODES) return;
    float4* hp = (float4*)(h + (size_t)n * 16);
    hp[0] = make_float4(x[n * 2 + 0], x[n * 2 + 1], 0.f, 0.f);
    hp[1] = make_float4(0.f, 0.f, 0.f, 0.f);
    hp[2] = make_float4(0.f, 0.f, 0.f, 0.f);
    hp[3] = make_float4(0.f, 0.f, 0.f, 0.f);
}

// ---------------------------------------------------------------------------
// CSR-by-destination build
// ---------------------------------------------------------------------------
__global__ void count_deg(const int* __restrict__ second, int* __restrict__ deg) {
    int i = blockIdx.x * blockDim.x + threadIdx.x;
    if (i < N_EDGES) atomicAdd(&deg[second[i]], 1);
}

__global__ void scan1(const int* __restrict__ deg, int* __restrict__ incl, int* __restrict__ bsum) {
    __shared__ int s[256];
    int t = threadIdx.x, i = blockIdx.x * 256 + t;
    int v = (i < N_NODES) ? deg[i] : 0;
    s[t] = v;
    __syncthreads();
    for (int d = 1; d < 256; d <<= 1) {
        int add = (t >= d) ? s[t - d] : 0;
        __syncthreads();
        s[t] += add;
        __syncthreads();
    }
    if (i < N_NODES) incl[i] = s[t];
    if (t == 255) bsum[blockIdx.x] = s[255];
}

__global__ void scan2(const int* __restrict__ bsum, int* __restrict__ bpre, int nblk) {
    __shared__ int s[256];
    int t = threadIdx.x;
    int v = (t < nblk) ? bsum[t] : 0;
    s[t] = v;
    __syncthreads();
    for (int d = 1; d < 256; d <<= 1) {
        int add = (t >= d) ? s[t - d] : 0;
        __syncthreads();
        s[t] += add;
        __syncthreads();
    }
    if (t < nblk) bpre[t] = s[t] - v;   // exclusive
}

__global__ void scan3(const int* __restrict__ incl, const int* __restrict__ deg,
                      const int* __restrict__ bpre, int* __restrict__ off, int* __restrict__ cursor) {
    int i = blockIdx.x * 256 + threadIdx.x;
    if (i < N_NODES) {
        int o = bpre[blockIdx.x] + incl[i] - deg[i];
        off[i] = o;
        cursor[i] = o;
    }
    if (i == 0) off[N_NODES] = N_EDGES;
}

__global__ void scatter_edges(const float* __restrict__ e, const int* __restrict__ first,
                              const int* __restrict__ second, int* __restrict__ cursor,
                              int* __restrict__ sfirst, float* __restrict__ se) {
    int i = blockIdx.x * blockDim.x + threadIdx.x;
    if (i >= N_EDGES) return;
    int d = second[i];
    int slot = atomicAdd(&cursor[d], 1);
    sfirst[slot] = first[i];
    se[slot] = e[i];
}

// ---------------------------------------------------------------------------
// Fused pass: per node (16 lanes), m = sum over in-edges of lerpA(e)@h_old[src]
// + lerp be(e); then GRU -> h_new. Zero atomics.
// ---------------------------------------------------------------------------
__global__ void edge_gru(const float* __restrict__ T, const unsigned short* __restrict__ D,
                         const float* __restrict__ beT,
                         const int* __restrict__ off, const int* __restrict__ sfirst,
                         const float* __restrict__ se,
                         const float* __restrict__ hOld, float* __restrict__ hNew,
                         const float* __restrict__ Wx, const float* __restrict__ Uh,
                         const float* __restrict__ bx, const float* __restrict__ bh) {
    __shared__ float sWx[768], sUh[768], sb[96];
    __shared__ float hg[16][16];
    __shared__ float sm[16][16];
    __shared__ float sh[16][16];
    for (int i = threadIdx.x; i < 768; i += 256) { sWx[i] = Wx[i]; sUh[i] = Uh[i]; }
    if (threadIdx.x < 48) { sb[threadIdx.x] = bx[threadIdx.x]; sb[48 + threadIdx.x] = bh[threadIdx.x]; }
    __syncthreads();

    int lane = threadIdx.x & 15;
    int grp  = threadIdx.x >> 4;
    int n = blockIdx.x * 16 + grp;            // grid sized exactly
    float hn = hOld[(size_t)n * 16 + lane];
    sh[grp][lane] = hn;

    float acc = 0.f;
    int s0 = off[n], s1 = off[n + 1];
    for (int idx = s0; idx < s1; ++idx) {
        float ev = se[idx];
        int  src = sfirst[idx];
        float s = ev * (float)TSIZE;
        int   t = (int)s;
        t = max(0, min(t, TSIZE - 1));
        float f = s - (float)t;

        hg[grp][lane] = hOld[(size_t)src * 16 + lane];  // same-wave lockstep

        const float4* A  = (const float4*)(T + (size_t)t * 256 + lane * 16);
        const uint4*  D4 = (const uint4*)(D + (size_t)t * 256 + lane * 16);
        float b0 = beT[t * NH + lane];
        float b1 = beT[(t + 1) * NH + lane];
        acc += b0 + f * (b1 - b0);

        uint4 dlo = D4[0], dhi = D4[1];
        const float* hq = hg[grp];
        float4 a0 = A[0], a1 = A[1], a2 = A[2], a3 = A[3];
        acc += (a0.x + f * bf_lo(dlo.x)) * hq[0];
        acc += (a0.y + f * bf_hi(dlo.x)) * hq[1];
        acc += (a0.z + f * bf_lo(dlo.y)) * hq[2];
        acc += (a0.w + f * bf_hi(dlo.y)) * hq[3];
        acc += (a1.x + f * bf_lo(dlo.z)) * hq[4];
        acc += (a1.y + f * bf_hi(dlo.z)) * hq[5];
        acc += (a1.z + f * bf_lo(dlo.w)) * hq[6];
        acc += (a1.w + f * bf_hi(dlo.w)) * hq[7];
        acc += (a2.x + f * bf_lo(dhi.x)) * hq[8];
        acc += (a2.y + f * bf_hi(dhi.x)) * hq[9];
        acc += (a2.z + f * bf_lo(dhi.y)) * hq[10];
        acc += (a2.w + f * bf_hi(dhi.y)) * hq[11];
        acc += (a3.x + f * bf_lo(dhi.z)) * hq[12];
        acc += (a3.y + f * bf_hi(dhi.z)) * hq[13];
        acc += (a3.z + f * bf_lo(dhi.w)) * hq[14];
        acc += (a3.w + f * bf_hi(dhi.w)) * hq[15];
    }
    sm[grp][lane] = acc;

    // GRU (reset_after=True); sm/sh written by same wave -> lockstep-safe
    float xz = sb[lane], xr = sb[16 + lane], xh = sb[32 + lane];
    float hz = sb[48 + lane], hr = sb[64 + lane], hhp = sb[80 + lane];
    #pragma unroll
    for (int k = 0; k < 16; ++k) {
        float mk = sm[grp][k], hk = sh[grp][k];
        xz  += mk * sWx[k * 48 + lane];
        xr  += mk * sWx[k * 48 + 16 + lane];
        xh  += mk * sWx[k * 48 + 32 + lane];
        hz  += hk * sUh[k * 48 + lane];
        hr  += hk * sUh[k * 48 + 16 + lane];
        hhp += hk * sUh[k * 48 + 32 + lane];
    }
    float z  = sigmoid_f(xz + hz);
    float r  = sigmoid_f(xr + hr);
    float hc = tanhf(xh + r * hhp);
    hNew[(size_t)n * 16 + lane] = z * hn + (1.f - z) * hc;
}

// ---------------------------------------------------------------------------
// Readout: block = 32 nodes, 256 threads = 2 halves x 128 columns.
// Outer-product: W streamed once per block; 32 node-accumulators per thread.
// ---------------------------------------------------------------------------
__global__ void readout(const float* __restrict__ h, const float* __restrict__ x,
                        const int* __restrict__ segment,
                        const float* __restrict__ W_i, const float* __restrict__ b_i,
                        const float* __restrict__ W_R, const float* __restrict__ b_R,
                        const float* __restrict__ W_j1, const float* __restrict__ b_j1,
                        const float* __restrict__ W_j2, const float* __restrict__ b_j2,
                        float* __restrict__ nb) {
    __shared__ float hx[RO][18];
    __shared__ float il[RO][RN];
    __shared__ float jl[RO][RN];
    int node0 = blockIdx.x * RO;
    int nn = min(RO, N_NODES - node0);
    int tid = threadIdx.x;

    for (int idx = tid; idx < RO * 18; idx += 256) {
        int n = idx / 18, k = idx % 18;
        float v = 0.f;
        if (n < nn)
            v = (k < 16) ? h[(size_t)(node0 + n) * 16 + k]
                         : x[(size_t)(node0 + n) * 2 + (k - 16)];
        hx[n][k] = v;
    }
    __syncthreads();

    int j = tid & 127, half = tid >> 7;
    float acc[RO];

    // layer 1
    {
        const float* W1 = half ? W_j1 : W_i;
        float bv = half ? b_j1[j] : b_i[j];
        #pragma unroll
        for (int n = 0; n < RO; ++n) acc[n] = bv;
        for (int k = 0; k < 18; ++k) {
            float w = W1[k * RN + j];
            #pragma unroll
            for (int n = 0; n < RO; ++n) acc[n] += hx[n][k] * w;
        }
        if (half == 0) {
            #pragma unroll
            for (int n = 0; n < RO; ++n) il[n][j] = tanhf(acc[n]);
        } else {
            #pragma unroll
            for (int n = 0; n < RO; ++n) jl[n][j] = selu_f(acc[n]);
        }
    }
    __syncthreads();

    // layer 2
    {
        const float* W2 = half ? W_j2 : W_R;
        float bv = half ? b_j2[j] : b_R[j];
        #pragma unroll
        for (int n = 0; n < RO; ++n) acc[n] = bv;
        const float (*src)[RN] = half ? jl : il;
        for (int k4 = 0; k4 < RN / 4; ++k4) {
            float w0 = W2[(k4 * 4 + 0) * RN + j];
            float w1 = W2[(k4 * 4 + 1) * RN + j];
            float w2 = W2[(k4 * 4 + 2) * RN + j];
            float w3 = W2[(k4 * 4 + 3) * RN + j];
            #pragma unroll
            for (int n = 0; n < RO; ++n) {
                float4 v = *(const float4*)&src[n][k4 * 4];
                acc[n] += v.x * w0 + v.y * w1 + v.z * w2 + v.w * w3;
            }
        }
        __syncthreads();
        if (half == 0) {
            #pragma unroll
            for (int n = 0; n < RO; ++n) il[n][j] = sigmoid_f(acc[n]);   // RR
        } else {
            #pragma unroll
            for (int n = 0; n < RO; ++n) jl[n][j] = acc[n];              // j2
        }
    }
    __syncthreads();

    if (half == 0) {
        float a = 0.f;
        int cur = segment[node0];
        for (int n = 0; n < nn; ++n) {
            int sg = segment[node0 + n];
            if (sg != cur) { atomicAdd(&nb[(size_t)cur * RN + j], a); a = 0.f; cur = sg; }
            a += il[n][j] * jl[n][j];
        }
        atomicAdd(&nb[(size_t)cur * RN + j], a);
    }
}

__global__ void final_head(const float* __restrict__ nb, const float* __restrict__ W_f1,
                           const float* __restrict__ b_f1, const float* __restrict__ W_f2,
                           const float* __restrict__ b_f2, float* __restrict__ out) {
    __shared__ float row[128];
    __shared__ float red[128];
    int g = blockIdx.x, j = threadIdx.x;
    row[j] = nb[(size_t)g * 128 + j];
    __syncthreads();
    float a = b_f1[j];
    for (int k = 0; k < 128; ++k)
        a += row[k] * W_f1[k * 128 + j];
    red[j] = selu_f(a) * W_f2[j];
    __syncthreads();
    for (int s2 = 64; s2 > 0; s2 >>= 1) {
        if (j < s2) red[j] += red[j + s2];
        __syncthreads();
    }
    if (j == 0) out[g] = red[0] + b_f2[0];
}

extern "C" void kernel_launch(void* const* d_in, const int* in_sizes, int n_in,
                              void* d_out, int out_size, void* d_ws, size_t ws_size,
                              hipStream_t stream) {
    const float* x    = (const float*)d_in[0];
    const float* e    = (const float*)d_in[1];
    const float* W_l1 = (const float*)d_in[2];
    const float* b_l1 = (const float*)d_in[3];
    const float* W_l2 = (const float*)d_in[4];
    const float* b_l2 = (const float*)d_in[5];
    const float* W_b1 = (const float*)d_in[6];
    const float* b_b1 = (const float*)d_in[7];
    const float* W_b2 = (const float*)d_in[8];
    const float* b_b2 = (const float*)d_in[9];
    const float* gWx  = (const float*)d_in[10];
    const float* gUh  = (const float*)d_in[11];
    const float* gbx  = (const float*)d_in[12];
    const float* gbh  = (const float*)d_in[13];
    const float* W_i  = (const float*)d_in[14];
    const float* b_i  = (const float*)d_in[15];
    const float* W_R  = (const float*)d_in[16];
    const float* b_R  = (const float*)d_in[17];
    const float* W_j1 = (const float*)d_in[18];
    const float* b_j1 = (const float*)d_in[19];
    const float* W_j2 = (const float*)d_in[20];
    const float* b_j2 = (const float*)d_in[21];
    const float* W_f1 = (const float*)d_in[22];
    const float* b_f1 = (const float*)d_in[23];
    const float* W_f2 = (const float*)d_in[24];
    const float* b_f2 = (const float*)d_in[25];
    const int* first   = (const int*)d_in[26];
    const int* second  = (const int*)d_in[27];
    const int* segment = (const int*)d_in[28];
    float* out = (float*)d_out;

    float* ws   = (float*)d_ws;
    float* T    = ws;                               // 2049*256
    float* beT  = T + (size_t)2049 * 256;           // 2049*16
    float* hA   = beT + 2049 * 16;                  // 800000
    float* hB   = hA + 800000;                      // 800000
    float* nb   = hB + 800000;                      // 64000
    int*   deg  = (int*)(nb + 64000);               // 50000
    int*   incl = deg + N_NODES;                    // 50000
    int*   off  = incl + N_NODES;                   // 50001
    int*   cur  = off + N_NODES + 1;                // 50000
    int*   bsum = cur + N_NODES;                    // 256
    int*   bpre = bsum + 256;                       // 256
    int*   sfirst = bpre + 256;                     // 800000
    float* se   = (float*)(sfirst + N_EDGES);       // 800000
    unsigned short* D = (unsigned short*)(se + N_EDGES);  // 2048*256 bf16

    const int NBLK = (N_NODES + 255) / 256;         // 196

    build_tables<<<TSIZE + 1, 256, 0, stream>>>(W_l1, b_l1, W_l2, b_l2,
                                                W_b1, b_b1, W_b2, b_b2, T, beT);
    build_diff<<<TSIZE, 256, 0, stream>>>(T, D);
    init_h<<<NBLK, 256, 0, stream>>>(x, hA);

    hipMemsetAsync(deg, 0, N_NODES * sizeof(int), stream);
    count_deg<<<N_EDGES / 256, 256, 0, stream>>>(second, deg);
    scan1<<<NBLK, 256, 0, stream>>>(deg, incl, bsum);
    scan2<<<1, 256, 0, stream>>>(bsum, bpre, NBLK);
    scan3<<<NBLK, 256, 0, stream>>>(incl, deg, bpre, off, cur);
    scatter_edges<<<N_EDGES / 256, 256, 0, stream>>>(e, first, second, cur, sfirst, se);

    float* hc = hA;
    float* hn = hB;
    for (int p = 0; p < 8; ++p) {
        edge_gru<<<N_NODES / 16, 256, 0, stream>>>(T, D, beT, off, sfirst, se,
                                                   hc, hn, gWx, gUh, gbx, gbh);
        float* tmp = hc; hc = hn; hn = tmp;
    }

    hipMemsetAsync(nb, 0, (size_t)N_GRAPHS * 128 * sizeof(float), stream);
    readout<<<(N_NODES + RO - 1) / RO, 256, 0, stream>>>(
        hc, x, segment, W_i, b_i, W_R, b_R, W_j1, b_j1, W_j2, b_j2, nb);
    final_head<<<N_GRAPHS, 128, 0, stream>>>(nb, W_f1, b_f1, W_f2, b_f2, out);
}

// Round 4
// 622.320 us; speedup vs baseline: 5.0268x; 1.7212x over previous
//
#include <hip/hip_runtime.h>
#include <hip/hip_fp16.h>
#include <math.h>

#define N_NODES  50000
#define N_EDGES  800000
#define N_GRAPHS 500
#define NH       16
#define MHID     256
#define RN       128
#define TSIZE    32          /* lerp intervals; err ~ a''*(1/32)^2/8 < 1e-4 */
#define RO       32

typedef _Float16 v2h __attribute__((ext_vector_type(2)));

__device__ __forceinline__ float selu_f(float v) {
    const float scale = 1.0507009873554805f;
    const float alpha = 1.6732632423543772f;
    return v > 0.f ? scale * v : scale * alpha * (expf(v) - 1.f);
}
__device__ __forceinline__ float sigmoid_f(float v) { return 1.f / (1.f + expf(-v)); }

__device__ __forceinline__ v2h u2h(unsigned u) {
    union { unsigned u; v2h h; } x; x.u = u; return x.h;
}
__device__ __forceinline__ unsigned h2u(v2h h) {
    union { unsigned u; v2h h; } x; x.h = h; return x.u;
}
// cvt_pkrtz returns a __fp16 vec2 on this toolchain; bit-cast into v2h.
__device__ __forceinline__ v2h pkrtz(float a, float b) {
    auto r = __builtin_amdgcn_cvt_pkrtz(a, b);
    union { decltype(r) i; v2h o; } u; u.i = r; return u.o;
}
__device__ __forceinline__ float fdot2(v2h a, v2h b, float c) {
    return __builtin_amdgcn_fdot2(a, b, c, false);
}

// ---------------------------------------------------------------------------
// Exact MLP eval at 33 grid points: aT[33][256] fp32, beT[33][16] fp32.
// ---------------------------------------------------------------------------
__global__ void build_tables(const float* __restrict__ W_l1, const float* __restrict__ b_l1,
                             const float* __restrict__ W_l2, const float* __restrict__ b_l2,
                             const float* __restrict__ W_b1, const float* __restrict__ b_b1,
                             const float* __restrict__ W_b2, const float* __restrict__ b_b2,
                             float* __restrict__ aT, float* __restrict__ beT) {
    __shared__ float hid[MHID];
    __shared__ float hidb[MHID];
    int t = blockIdx.x;          // 0..TSIZE
    int j = threadIdx.x;         // 0..255
    float ev = (float)t / (float)TSIZE;
    hid[j]  = selu_f(ev * W_l1[j] + b_l1[j]);
    hidb[j] = selu_f(ev * W_b1[j] + b_b1[j]);
    __syncthreads();
    float acc = b_l2[j];
    for (int k = 0; k < MHID; ++k)
        acc += hid[k] * W_l2[k * 256 + j];
    aT[(size_t)t * 256 + j] = acc;
    if (j < NH) {
        float accb = b_b2[j];
        for (int k = 0; k < MHID; ++k)
            accb += hidb[k] * W_b2[k * NH + j];
        beT[t * NH + j] = accb;
    }
}

// ---------------------------------------------------------------------------
// Pack fp16 LDS image: 16 planes (one per output row i), plane stride 1104 B
// (276 words; 276%32==20 -> 16 lanes' b128 starts cover 8 distinct bank-quads
// => conflict-free). Plane = 33 rows x 16 half (rows t, t+1 contiguous).
// Appended at byte 17664: beP[32][16] u32 = half2(be[t][i], be[t+1][i]).
// ---------------------------------------------------------------------------
__global__ void pack_tables(const float* __restrict__ aT, const float* __restrict__ beT,
                            unsigned short* __restrict__ img) {
    int t = blockIdx.x;          // 0..32
    int j = threadIdx.x;         // 0..255
    int i = j >> 4, k = j & 15;
    img[i * 552 + t * 16 + k] = __half_as_ushort(__float2half(aT[(size_t)t * 256 + j]));
    if (t < TSIZE && j < 16) {
        img[8832 + (t * 16 + j) * 2 + 0] = __half_as_ushort(__float2half(beT[t * 16 + j]));
        img[8832 + (t * 16 + j) * 2 + 1] = __half_as_ushort(__float2half(beT[(t + 1) * 16 + j]));
    }
}

__global__ void init_h(const float* __restrict__ x, float* __restrict__ h) {
    int n = blockIdx.x * blockDim.x + threadIdx.x;
    if (n >= N_NODES) return;
    float4* hp = (float4*)(h + (size_t)n * 16);
    hp[0] = make_float4(x[n * 2 + 0], x[n * 2 + 1], 0.f, 0.f);
    hp[1] = make_float4(0.f, 0.f, 0.f, 0.f);
    hp[2] = make_float4(0.f, 0.f, 0.f, 0.f);
    hp[3] = make_float4(0.f, 0.f, 0.f, 0.f);
}

// ---------------------------------------------------------------------------
// CSR-by-destination build
// ---------------------------------------------------------------------------
__global__ void count_deg(const int* __restrict__ second, int* __restrict__ deg) {
    int i = blockIdx.x * blockDim.x + threadIdx.x;
    if (i < N_EDGES) atomicAdd(&deg[second[i]], 1);
}

__global__ void scan1(const int* __restrict__ deg, int* __restrict__ incl, int* __restrict__ bsum) {
    __shared__ int s[256];
    int t = threadIdx.x, i = blockIdx.x * 256 + t;
    int v = (i < N_NODES) ? deg[i] : 0;
    s[t] = v;
    __syncthreads();
    for (int d = 1; d < 256; d <<= 1) {
        int add = (t >= d) ? s[t - d] : 0;
        __syncthreads();
        s[t] += add;
        __syncthreads();
    }
    if (i < N_NODES) incl[i] = s[t];
    if (t == 255) bsum[blockIdx.x] = s[255];
}

__global__ void scan2(const int* __restrict__ bsum, int* __restrict__ bpre, int nblk) {
    __shared__ int s[256];
    int t = threadIdx.x;
    int v = (t < nblk) ? bsum[t] : 0;
    s[t] = v;
    __syncthreads();
    for (int d = 1; d < 256; d <<= 1) {
        int add = (t >= d) ? s[t - d] : 0;
        __syncthreads();
        s[t] += add;
        __syncthreads();
    }
    if (t < nblk) bpre[t] = s[t] - v;   // exclusive
}

__global__ void scan3(const int* __restrict__ incl, const int* __restrict__ deg,
                      const int* __restrict__ bpre, int* __restrict__ off, int* __restrict__ cursor) {
    int i = blockIdx.x * 256 + threadIdx.x;
    if (i < N_NODES) {
        int o = bpre[blockIdx.x] + incl[i] - deg[i];
        off[i] = o;
        cursor[i] = o;
    }
    if (i == 0) off[N_NODES] = N_EDGES;
}

__global__ void scatter_edges(const float* __restrict__ e, const int* __restrict__ first,
                              const int* __restrict__ second, int* __restrict__ cursor,
                              int2* __restrict__ em) {
    int i = blockIdx.x * blockDim.x + threadIdx.x;
    if (i >= N_EDGES) return;
    int d = second[i];
    int slot = atomicAdd(&cursor[d], 1);
    em[slot] = make_int2(__float_as_int(e[i]), first[i]);
}

// ---------------------------------------------------------------------------
// Fused pass: 16 lanes per node; per in-edge m += lerpA(e)@h[src] + lerp be(e)
// with fp16 table in LDS + v_dot2_f32_f16; then GRU -> h_new. Zero atomics.
// ---------------------------------------------------------------------------
__global__ void edge_gru(const uint4* __restrict__ img4,
                         const int* __restrict__ off, const int2* __restrict__ em,
                         const float* __restrict__ hOld, float* __restrict__ hNew,
                         const float* __restrict__ Wx, const float* __restrict__ Uh,
                         const float* __restrict__ bx, const float* __restrict__ bh) {
    __shared__ uint4 sImg[1232];        // 17664B T-planes + 2048B beP
    __shared__ float sWx[768], sUh[768], sb[96];
    __shared__ float sm[16][16], sh[16][16];
    __shared__ unsigned hgp[16][8];

    for (int i = threadIdx.x; i < 1232; i += 256) sImg[i] = img4[i];
    for (int i = threadIdx.x; i < 768; i += 256) { sWx[i] = Wx[i]; sUh[i] = Uh[i]; }
    if (threadIdx.x < 48) { sb[threadIdx.x] = bx[threadIdx.x]; sb[48 + threadIdx.x] = bh[threadIdx.x]; }
    __syncthreads();

    int lane = threadIdx.x & 15;
    int grp  = threadIdx.x >> 4;
    int n = blockIdx.x * 16 + grp;            // grid sized exactly
    float hn = hOld[(size_t)n * 16 + lane];
    sh[grp][lane] = hn;

    const unsigned* sbeP = (const unsigned*)(sImg + 1104);

    float acc = 0.f;
    int s0 = off[n], s1 = off[n + 1];
    if (s0 < s1) {
        int2 me = em[s0];
        for (int idx = s0; idx < s1; ++idx) {
            float ev = __int_as_float(me.x);
            int  src = me.y;
            if (idx + 1 < s1) me = em[idx + 1];     // prefetch next meta

            // issue h gather early (float2; lanes 8..15 duplicate 0..7 -> same line)
            float2 hp = *(const float2*)(hOld + (size_t)src * 16 + (lane & 7) * 2);

            float s = ev * (float)TSIZE;
            int   t = (int)s;
            t = max(0, min(t, TSIZE - 1));
            float f = s - (float)t;

            // table rows t, t+1 (contiguous 64B), conflict-free b128s
            const uint4* Tp = sImg + (unsigned)lane * 69u + (unsigned)t * 2u;
            uint4 r0 = Tp[0], r1 = Tp[1];   // row t   : pairs a0..a7
            uint4 r2 = Tp[2], r3 = Tp[3];   // row t+1

            v2h f2 = pkrtz(f, f);
            // share h as half2 pairs
            hgp[grp][lane & 7] = h2u(pkrtz(hp.x, hp.y));
            const uint4* Hp = (const uint4*)hgp[grp];
            uint4 h0 = Hp[0], h1 = Hp[1];

            v2h a;
            a = u2h(r0.x); a = a + f2 * (u2h(r2.x) - a); acc = fdot2(a, u2h(h0.x), acc);
            a = u2h(r0.y); a = a + f2 * (u2h(r2.y) - a); acc = fdot2(a, u2h(h0.y), acc);
            a = u2h(r0.z); a = a + f2 * (u2h(r2.z) - a); acc = fdot2(a, u2h(h0.z), acc);
            a = u2h(r0.w); a = a + f2 * (u2h(r2.w) - a); acc = fdot2(a, u2h(h0.w), acc);
            a = u2h(r1.x); a = a + f2 * (u2h(r3.x) - a); acc = fdot2(a, u2h(h1.x), acc);
            a = u2h(r1.y); a = a + f2 * (u2h(r3.y) - a); acc = fdot2(a, u2h(h1.y), acc);
            a = u2h(r1.z); a = a + f2 * (u2h(r3.z) - a); acc = fdot2(a, u2h(h1.z), acc);
            a = u2h(r1.w); a = a + f2 * (u2h(r3.w) - a); acc = fdot2(a, u2h(h1.w), acc);

            // bias lerp: be0*(1-f) + be1*f
            acc = fdot2(u2h(sbeP[t * 16 + lane]), pkrtz(1.f - f, f), acc);
        }
    }
    sm[grp][lane] = acc;

    // GRU (reset_after=True); sm/sh same-wave lockstep
    float xz = sb[lane], xr = sb[16 + lane], xh = sb[32 + lane];
    float hz = sb[48 + lane], hr = sb[64 + lane], hhp = sb[80 + lane];
    #pragma unroll
    for (int k = 0; k < 16; ++k) {
        float mk = sm[grp][k], hk = sh[grp][k];
        xz  += mk * sWx[k * 48 + lane];
        xr  += mk * sWx[k * 48 + 16 + lane];
        xh  += mk * sWx[k * 48 + 32 + lane];
        hz  += hk * sUh[k * 48 + lane];
        hr  += hk * sUh[k * 48 + 16 + lane];
        hhp += hk * sUh[k * 48 + 32 + lane];
    }
    float z  = sigmoid_f(xz + hz);
    float r  = sigmoid_f(xr + hr);
    float hc = tanhf(xh + r * hhp);
    hNew[(size_t)n * 16 + lane] = z * hn + (1.f - z) * hc;
}

// ---------------------------------------------------------------------------
// Readout (unchanged from R2): block = 32 nodes, 256 threads = 2 halves x 128.
// ---------------------------------------------------------------------------
__global__ void readout(const float* __restrict__ h, const float* __restrict__ x,
                        const int* __restrict__ segment,
                        const float* __restrict__ W_i, const float* __restrict__ b_i,
                        const float* __restrict__ W_R, const float* __restrict__ b_R,
                        const float* __restrict__ W_j1, const float* __restrict__ b_j1,
                        const float* __restrict__ W_j2, const float* __restrict__ b_j2,
                        float* __restrict__ nb) {
    __shared__ float hx[RO][18];
    __shared__ float il[RO][RN];
    __shared__ float jl[RO][RN];
    int node0 = blockIdx.x * RO;
    int nn = min(RO, N_NODES - node0);
    int tid = threadIdx.x;

    for (int idx = tid; idx < RO * 18; idx += 256) {
        int n = idx / 18, k = idx % 18;
        float v = 0.f;
        if (n < nn)
            v = (k < 16) ? h[(size_t)(node0 + n) * 16 + k]
                         : x[(size_t)(node0 + n) * 2 + (k - 16)];
        hx[n][k] = v;
    }
    __syncthreads();

    int j = tid & 127, half = tid >> 7;
    float acc[RO];

    {
        const float* W1 = half ? W_j1 : W_i;
        float bv = half ? b_j1[j] : b_i[j];
        #pragma unroll
        for (int n = 0; n < RO; ++n) acc[n] = bv;
        for (int k = 0; k < 18; ++k) {
            float w = W1[k * RN + j];
            #pragma unroll
            for (int n = 0; n < RO; ++n) acc[n] += hx[n][k] * w;
        }
        if (half == 0) {
            #pragma unroll
            for (int n = 0; n < RO; ++n) il[n][j] = tanhf(acc[n]);
        } else {
            #pragma unroll
            for (int n = 0; n < RO; ++n) jl[n][j] = selu_f(acc[n]);
        }
    }
    __syncthreads();

    {
        const float* W2 = half ? W_j2 : W_R;
        float bv = half ? b_j2[j] : b_R[j];
        #pragma unroll
        for (int n = 0; n < RO; ++n) acc[n] = bv;
        const float (*src)[RN] = half ? jl : il;
        for (int k4 = 0; k4 < RN / 4; ++k4) {
            float w0 = W2[(k4 * 4 + 0) * RN + j];
            float w1 = W2[(k4 * 4 + 1) * RN + j];
            float w2 = W2[(k4 * 4 + 2) * RN + j];
            float w3 = W2[(k4 * 4 + 3) * RN + j];
            #pragma unroll
            for (int n = 0; n < RO; ++n) {
                float4 v = *(const float4*)&src[n][k4 * 4];
                acc[n] += v.x * w0 + v.y * w1 + v.z * w2 + v.w * w3;
            }
        }
        __syncthreads();
        if (half == 0) {
            #pragma unroll
            for (int n = 0; n < RO; ++n) il[n][j] = sigmoid_f(acc[n]);   // RR
        } else {
            #pragma unroll
            for (int n = 0; n < RO; ++n) jl[n][j] = acc[n];              // j2
        }
    }
    __syncthreads();

    if (half == 0) {
        float a = 0.f;
        int cur = segment[node0];
        for (int n = 0; n < nn; ++n) {
            int sg = segment[node0 + n];
            if (sg != cur) { atomicAdd(&nb[(size_t)cur * RN + j], a); a = 0.f; cur = sg; }
            a += il[n][j] * jl[n][j];
        }
        atomicAdd(&nb[(size_t)cur * RN + j], a);
    }
}

__global__ void final_head(const float* __restrict__ nb, const float* __restrict__ W_f1,
                           const float* __restrict__ b_f1, const float* __restrict__ W_f2,
                           const float* __restrict__ b_f2, float* __restrict__ out) {
    __shared__ float row[128];
    __shared__ float red[128];
    int g = blockIdx.x, j = threadIdx.x;
    row[j] = nb[(size_t)g * 128 + j];
    __syncthreads();
    float a = b_f1[j];
    for (int k = 0; k < 128; ++k)
        a += row[k] * W_f1[k * 128 + j];
    red[j] = selu_f(a) * W_f2[j];
    __syncthreads();
    for (int s2 = 64; s2 > 0; s2 >>= 1) {
        if (j < s2) red[j] += red[j + s2];
        __syncthreads();
    }
    if (j == 0) out[g] = red[0] + b_f2[0];
}

extern "C" void kernel_launch(void* const* d_in, const int* in_sizes, int n_in,
                              void* d_out, int out_size, void* d_ws, size_t ws_size,
                              hipStream_t stream) {
    const float* x    = (const float*)d_in[0];
    const float* e    = (const float*)d_in[1];
    const float* W_l1 = (const float*)d_in[2];
    const float* b_l1 = (const float*)d_in[3];
    const float* W_l2 = (const float*)d_in[4];
    const float* b_l2 = (const float*)d_in[5];
    const float* W_b1 = (const float*)d_in[6];
    const float* b_b1 = (const float*)d_in[7];
    const float* W_b2 = (const float*)d_in[8];
    const float* b_b2 = (const float*)d_in[9];
    const float* gWx  = (const float*)d_in[10];
    const float* gUh  = (const float*)d_in[11];
    const float* gbx  = (const float*)d_in[12];
    const float* gbh  = (const float*)d_in[13];
    const float* W_i  = (const float*)d_in[14];
    const float* b_i  = (const float*)d_in[15];
    const float* W_R  = (const float*)d_in[16];
    const float* b_R  = (const float*)d_in[17];
    const float* W_j1 = (const float*)d_in[18];
    const float* b_j1 = (const float*)d_in[19];
    const float* W_j2 = (const float*)d_in[20];
    const float* b_j2 = (const float*)d_in[21];
    const float* W_f1 = (const float*)d_in[22];
    const float* b_f1 = (const float*)d_in[23];
    const float* W_f2 = (const float*)d_in[24];
    const float* b_f2 = (const float*)d_in[25];
    const int* first   = (const int*)d_in[26];
    const int* second  = (const int*)d_in[27];
    const int* segment = (const int*)d_in[28];
    float* out = (float*)d_out;

    float* ws   = (float*)d_ws;
    float* aT   = ws;                               // 33*256 = 8448
    float* beT  = aT + 33 * 256;                    // 33*16 = 528
    float* img  = beT + 528;                        // 19712B = 4928 floats (16B-aligned)
    float* hA   = img + 4928;                       // 800000
    float* hB   = hA + 800000;                      // 800000
    float* nb   = hB + 800000;                      // 64000
    int*   deg  = (int*)(nb + 64000);               // 50000
    int*   incl = deg + N_NODES;                    // 50000
    int*   off  = incl + N_NODES;                   // 50001
    int*   cur  = off + N_NODES + 1;                // 50000
    int*   bsum = cur + N_NODES;                    // 256
    int*   bpre = bsum + 256;                       // 256
    int*   emB  = bpre + 256;                       // align to 16B for int2
    int2*  em   = (int2*)(((size_t)(emB) + 15) & ~(size_t)15);   // 800000 int2

    const int NBLK = (N_NODES + 255) / 256;         // 196

    build_tables<<<TSIZE + 1, 256, 0, stream>>>(W_l1, b_l1, W_l2, b_l2,
                                                W_b1, b_b1, W_b2, b_b2, aT, beT);
    pack_tables<<<TSIZE + 1, 256, 0, stream>>>(aT, beT, (unsigned short*)img);
    init_h<<<NBLK, 256, 0, stream>>>(x, hA);

    hipMemsetAsync(deg, 0, N_NODES * sizeof(int), stream);
    count_deg<<<N_EDGES / 256, 256, 0, stream>>>(second, deg);
    scan1<<<NBLK, 256, 0, stream>>>(deg, incl, bsum);
    scan2<<<1, 256, 0, stream>>>(bsum, bpre, NBLK);
    scan3<<<NBLK, 256, 0, stream>>>(incl, deg, bpre, off, cur);
    scatter_edges<<<N_EDGES / 256, 256, 0, stream>>>(e, first, second, cur, em);

    float* hc = hA;
    float* hn = hB;
    for (int p = 0; p < 8; ++p) {
        edge_gru<<<N_NODES / 16, 256, 0, stream>>>((const uint4*)img, off, em,
                                                   hc, hn, gWx, gUh, gbx, gbh);
        float* tmp = hc; hc = hn; hn = tmp;
    }

    hipMemsetAsync(nb, 0, (size_t)N_GRAPHS * 128 * sizeof(float), stream);
    readout<<<(N_NODES + RO - 1) / RO, 256, 0, stream>>>(
        hc, x, segment, W_i, b_i, W_R, b_R, W_j1, b_j1, W_j2, b_j2, nb);
    final_head<<<N_GRAPHS, 128, 0, stream>>>(nb, W_f1, b_f1, W_f2, b_f2, out);
}